// Round 14
// baseline (130.440 us; speedup 1.0000x reference)
//
#include <hip/hip_runtime.h>

#define TSEQ 2304
#define DIN  1024
#define NH   8
#define DD   64
#define NC   1536
#define MROWS 4608
#define L2E  1.44269504f
#define EF   2.71828183f

typedef __attribute__((ext_vector_type(8))) short bf16x8;
typedef __attribute__((ext_vector_type(4))) float f32x4;
typedef __attribute__((ext_vector_type(16))) float f32x16;
typedef __attribute__((ext_vector_type(4))) unsigned short u16x4;
typedef __attribute__((ext_vector_type(4))) unsigned int u32x4;

__device__ __forceinline__ unsigned short f2bf(float f){
    union { float f; unsigned int u; } x; x.f = f;
    unsigned int r = x.u + 0x7FFFu + ((x.u >> 16) & 1u);
    return (unsigned short)(r >> 16);
}

// raw v_exp_f32: D = 2^S0, no libm guard code (inputs bounded +-10 here)
__device__ __forceinline__ float exp2raw(float x){
    float r;
    asm("v_exp_f32 %0, %1" : "=v"(r) : "v"(x));
    return r;
}

// two f32 -> packed [bf16(b):bf16(a)] in one VALU op
__device__ __forceinline__ unsigned int cvtpk(float a, float b){
    unsigned int r;
    asm("v_cvt_pk_bf16_f32 %0, %1, %2" : "=v"(r) : "v"(a), "v"(b));
    return r;
}

__device__ __forceinline__ void gload_lds16(const void* g, void* l){
    __builtin_amdgcn_global_load_lds(
        (const __attribute__((address_space(1))) void*)g,
        (__attribute__((address_space(3))) void*)l, 16, 0, 0);
}

struct WArgs {
    const float* W[9];   // [seg*3+proj], seg0=s, seg1=m, seg2=e; proj0=q,1=k,2=v
    const float* g[3];
    const float* bv[3];
};

// Fused preprocessing: blocks [0,1152) build Wb, [1152,1224) bias, [1224,5832) LN
__global__ __launch_bounds__(256) void k_pre(WArgs a, const float* __restrict__ x,
                                             unsigned short* __restrict__ wb,
                                             float* __restrict__ bias,
                                             unsigned short* __restrict__ nrm)
{
    __shared__ float lds[64][65];
    __shared__ float red[4][64];
    __shared__ float r1[4], r2[4];
    const int bid = blockIdx.x;
    const int tid = threadIdx.x;
    if (bid < 1152){
        const int dt = bid & 15, h = (bid >> 4) & 7, sp = bid >> 7;
        const int seg = sp / 3, proj = sp % 3;
        const float* W = a.W[seg*3 + proj];
        const float* g = a.g[seg];
        const int d0 = dt * 64;
        {
            const int e = tid & 63, rq = tid >> 6;
#pragma unroll
            for (int rr = 0; rr < 16; ++rr){
                const int dl = rr*4 + rq;
                lds[dl][e] = W[((size_t)h*DIN + d0 + dl)*DD + e];
            }
        }
        __syncthreads();
        {
            const int dl = tid & 63, eq = tid >> 6;
            const int n0 = proj*512 + h*64;
            const float gv = g[h*DIN + d0 + dl];
#pragma unroll
            for (int rr = 0; rr < 16; ++rr){
                const int el = eq*16 + rr;
                wb[((size_t)seg*NC + n0 + el)*DIN + d0 + dl] = f2bf(lds[dl][el] * gv);
            }
        }
    } else if (bid < 1224){
        const int u = bid - 1152;
        const int h = u & 7, sp = u >> 3;
        const int seg = sp / 3, proj = sp % 3;
        const float* W  = a.W[seg*3 + proj];
        const float* bv = a.bv[seg];
        const int e = tid & 63, dc = tid >> 6;
        float sum = 0.f;
        for (int i = 0; i < 256; ++i){
            const int d = dc*256 + i;
            sum += bv[h*DIN + d] * W[((size_t)h*DIN + d)*DD + e];
        }
        red[dc][e] = sum;
        __syncthreads();
        if (dc == 0)
            bias[seg*NC + proj*512 + h*64 + e] = red[0][e] + red[1][e] + red[2][e] + red[3][e];
    } else {
        const int row = bid - 1224;
        const float* xr = x + (size_t)row * DIN;
        f32x4 v = *(const f32x4*)&xr[tid*4];
        float s1 = v[0]+v[1]+v[2]+v[3];
        float s2 = v[0]*v[0]+v[1]*v[1]+v[2]*v[2]+v[3]*v[3];
#pragma unroll
        for (int m = 1; m < 64; m <<= 1){ s1 += __shfl_xor(s1, m); s2 += __shfl_xor(s2, m); }
        const int wid = tid >> 6;
        if ((tid & 63) == 0){ r1[wid] = s1; r2[wid] = s2; }
        __syncthreads();
        s1 = r1[0]+r1[1]+r1[2]+r1[3];
        s2 = r2[0]+r2[1]+r2[2]+r2[3];
        const float mean = s1 * (1.f/1024.f);
        const float var  = s2 * (1.f/1024.f) - mean*mean;
        const float rstd = rsqrtf(var + 1e-5f);
        u16x4 ov;
#pragma unroll
        for (int j = 0; j < 4; ++j) ov[j] = f2bf((v[j]-mean)*rstd);
        *(u16x4*)&nrm[(size_t)row*DIN + tid*4] = ov;
    }
}

// C[4608][1536] = nrm @ Wb[seg]^T + bias; q,k scattered to [b][h][t][64];
// V written DIRECTLY TRANSPOSED to vt[b][h][e][t]. q pre-scaled by 0.125*log2e.
// BK=64; [128][64] LDS with XOR slot swizzle via pre-swizzled global source.
__global__ __launch_bounds__(256) void k_gemm(
    const unsigned short* __restrict__ A,
    const unsigned short* __restrict__ Wb,
    const float* __restrict__ bias,
    unsigned short* __restrict__ qo,
    unsigned short* __restrict__ ko,
    unsigned short* __restrict__ vt)
{
    __shared__ unsigned short As[128*64];
    __shared__ unsigned short Bs[128*64];
    const int mt = blockIdx.x, nt = blockIdx.y;
    const int row0 = mt*128, n0 = nt*128;
    const int rloc = row0 % TSEQ;
    const int seg = (rloc < 128) ? 0 : (rloc < 2176 ? 1 : 2);
    const unsigned short* Bp = Wb + (size_t)seg * NC * DIN;
    const int tid = threadIdx.x;
    const int wid = tid >> 6, lane = tid & 63;
    const int wr = wid >> 1, wc = wid & 1;
    const int lr = lane & 15, lg = lane >> 4;
    const int rsub = lane >> 3;
    const int cgx  = (lane & 7) ^ rsub;
    f32x4 acc[4][4];
#pragma unroll
    for (int m = 0; m < 4; ++m)
#pragma unroll
        for (int n = 0; n < 4; ++n) acc[m][n] = (f32x4){0.f,0.f,0.f,0.f};

    for (int kt = 0; kt < DIN/64; ++kt){
        const int k0 = kt*64;
        __syncthreads();
#pragma unroll
        for (int i = 0; i < 4; ++i){
            const int c = wid*4 + i;
            const int r = c*8 + rsub;
            gload_lds16(&A [(size_t)(row0 + r)*DIN + k0 + cgx*8], &As[c*512]);
            gload_lds16(&Bp[(size_t)(n0  + r)*DIN + k0 + cgx*8], &Bs[c*512]);
        }
        __syncthreads();
#pragma unroll
        for (int ks = 0; ks < 2; ++ks){
            bf16x8 af[4], bfr[4];
#pragma unroll
            for (int m = 0; m < 4; ++m)
                af[m]  = *(const bf16x8*)&As[(wr*64 + m*16 + lr)*64 + (((ks*4 + lg) ^ (lr & 7))*8)];
#pragma unroll
            for (int n = 0; n < 4; ++n)
                bfr[n] = *(const bf16x8*)&Bs[(wc*64 + n*16 + lr)*64 + (((ks*4 + lg) ^ (lr & 7))*8)];
#pragma unroll
            for (int m = 0; m < 4; ++m)
#pragma unroll
                for (int n = 0; n < 4; ++n)
                    acc[m][n] = __builtin_amdgcn_mfma_f32_16x16x32_bf16(af[m], bfr[n], acc[m][n], 0, 0, 0);
        }
    }
    const int b_ = row0 / TSEQ;
    const int t0 = row0 - b_ * TSEQ;
#pragma unroll
    for (int m = 0; m < 4; ++m){
#pragma unroll
        for (int n = 0; n < 4; ++n){
            const int nglob = n0 + wc*64 + n*16 + lr;
            const float bs = bias[seg*NC + nglob];
            const int proj = nglob >> 9, hh = (nglob >> 6) & 7, e = nglob & 63;
            if (proj < 2){
                unsigned short* op = (proj == 0) ? qo : ko;
                const float scale = (proj == 0) ? 0.125f * L2E : 1.0f;
                const size_t ob = ((size_t)(b_*NH + hh) * TSEQ) * DD + e;
#pragma unroll
                for (int j = 0; j < 4; ++j){
                    const int t = t0 + wr*64 + m*16 + 4*lg + j;
                    op[ob + (size_t)t * DD] = f2bf((acc[m][n][j] + bs) * scale);
                }
            } else {
                unsigned short* vp = vt + ((size_t)(b_*NH + hh)*DD + e)*TSEQ;
                const int t = t0 + wr*64 + m*16 + 4*lg;
                u16x4 pk;
#pragma unroll
                for (int j = 0; j < 4; ++j) pk[j] = f2bf(acc[m][n][j] + bs);
                *(u16x4*)&vp[t] = pk;
            }
        }
    }
}

// Flash attention, barrier-free main loop: intra-block split-K.
// Block = 32 q-rows, 4 waves; wave w owns k-tiles [9w, 9w+9), reading K/V
// fragments DIRECTLY from global (L1/L2-served; no LDS, no syncthreads in
// the loop -> compiler fully unrolls 9 tiles and pipelines loads freely).
// 32x32 swapped QK^T, in-register P (cvt_pk + permlane32_swap). End: one
// LDS reduction across the 4 waves, normalize, write final out directly.
// Grid 1D 1152, bh-pinned XCD swizzle: bid = ((bh>>3)*72 + qtb)*8 + (bh&7).
__global__ __launch_bounds__(256) void k_attn(
    const unsigned short* __restrict__ Q,
    const unsigned short* __restrict__ K,
    const unsigned short* __restrict__ Vt,
    float* __restrict__ out)
{
    __shared__ float osum[4][32][64];
    __shared__ float lsums[4][32];
    const int bid = blockIdx.x;
    const int bhLo = bid & 7;
    const int rdec = bid >> 3;
    const int qtb  = rdec % 72;
    const int bh   = (rdec / 72) * 8 + bhLo;
    const int tid  = threadIdx.x;
    const int w    = tid >> 6;
    const int lane = tid & 63;
    const int l31  = lane & 31;
    const int h    = lane >> 5;
    const size_t qkb = (size_t)bh * TSEQ * DD;
    const size_t vtb = (size_t)bh * DD * TSEQ;
    const int q0 = qtb * 32;
    const int kd = qtb >> 1;            // diagonal k-tile (uniform for block)
    const int kt0 = w * 9, kt1 = kt0 + 9;

    // Q fragments (B-operand): col = q0 + l31, k-slice ds*16 + h*8
    bf16x8 aq[4];
#pragma unroll
    for (int ds = 0; ds < 4; ++ds)
        aq[ds] = *(const bf16x8*)&Q[qkb + (size_t)(q0 + l31)*DD + ds*16 + h*8];

    float lsum = 0.f;
    f32x16 o0, o1;
#pragma unroll
    for (int r = 0; r < 16; ++r){ o0[r] = 0.f; o1[r] = 0.f; }

    const unsigned short* Krow0 = K  + qkb + (size_t)l31 * DD;        // + kc0*DD
    const unsigned short* Vrow  = Vt + vtb + (size_t)l31 * TSEQ;      // + kc0

    for (int kt = kt0; kt < kt1; ++kt){
        const int kc0 = kt*64;
        // K fragments: A-operand rows kk = kc0 + l31 (+32), slices (ds,h)
        bf16x8 kf0[4], kf1[4], vf0[4], vf1[4];
#pragma unroll
        for (int ds = 0; ds < 4; ++ds){
            kf0[ds] = *(const bf16x8*)&Krow0[(size_t)(kc0)*DD      + ds*16 + h*8];
            kf1[ds] = *(const bf16x8*)&Krow0[(size_t)(kc0 + 32)*DD + ds*16 + h*8];
        }
#pragma unroll
        for (int ks = 0; ks < 4; ++ks){
            vf0[ks] = *(const bf16x8*)&Vrow[kc0 + ks*16 + h*8];
            vf1[ks] = *(const bf16x8*)&Vrow[(size_t)32*TSEQ + kc0 + ks*16 + h*8];
        }
        // QK^T: s0 = S^T[kk 0..31][q], s1 = S^T[kk 32..63][q]
        f32x16 s0, s1;
#pragma unroll
        for (int r = 0; r < 16; ++r){ s0[r] = 0.f; s1[r] = 0.f; }
#pragma unroll
        for (int ds = 0; ds < 4; ++ds){
            s0 = __builtin_amdgcn_mfma_f32_32x32x16_bf16(kf0[ds], aq[ds], s0, 0, 0, 0);
            s1 = __builtin_amdgcn_mfma_f32_32x32x16_bf16(kf1[ds], aq[ds], s1, 0, 0, 0);
        }
        // softmax numerators (deferred tril bias: x e at diagonal)
        if (kt == kd){
            lsum *= EF;
#pragma unroll
            for (int r = 0; r < 16; ++r){ o0[r] *= EF; o1[r] *= EF; }
            const int qr = q0 + l31;
#pragma unroll
            for (int r = 0; r < 16; ++r){
                const int kk = kc0 + (r&3) + 8*(r>>2) + 4*h;
                const float p0 = exp2raw(s0[r] + ((kk      <= qr) ? L2E : 0.f));
                const float p1 = exp2raw(s1[r] + ((kk + 32 <= qr) ? L2E : 0.f));
                s0[r] = p0; s1[r] = p1;
                lsum += p0 + p1;
            }
        } else {
#pragma unroll
            for (int r = 0; r < 16; ++r){
                const float p0 = exp2raw(s0[r]);
                const float p1 = exp2raw(s1[r]);
                s0[r] = p0; s1[r] = p1;
                lsum += p0 + p1;
            }
        }
        // PV: build A-frag in-register (cvt_pk + permlane32_swap) per 16-k step
#pragma unroll
        for (int ks = 0; ks < 4; ++ks){
            const int rb = (ks & 1) * 8;
            unsigned int a01, a23, b01, b23;
            if (ks < 2){
                a01 = cvtpk(s0[rb+0], s0[rb+1]); a23 = cvtpk(s0[rb+2], s0[rb+3]);
                b01 = cvtpk(s0[rb+4], s0[rb+5]); b23 = cvtpk(s0[rb+6], s0[rb+7]);
            } else {
                a01 = cvtpk(s1[rb+0], s1[rb+1]); a23 = cvtpk(s1[rb+2], s1[rb+3]);
                b01 = cvtpk(s1[rb+4], s1[rb+5]); b23 = cvtpk(s1[rb+6], s1[rb+7]);
            }
            asm("v_permlane32_swap_b32 %0, %1" : "+v"(a01), "+v"(b01));
            asm("v_permlane32_swap_b32 %0, %1" : "+v"(a23), "+v"(b23));
            u32x4 fw; fw[0] = a01; fw[1] = a23; fw[2] = b01; fw[3] = b23;
            bf16x8 pa = __builtin_bit_cast(bf16x8, fw);
            o0 = __builtin_amdgcn_mfma_f32_32x32x16_bf16(pa, vf0[ks], o0, 0, 0, 0);
            o1 = __builtin_amdgcn_mfma_f32_32x32x16_bf16(pa, vf1[ks], o1, 0, 0, 0);
        }
    }
    if (kd >= kt1){
        lsum *= EF;
#pragma unroll
        for (int r = 0; r < 16; ++r){ o0[r] *= EF; o1[r] *= EF; }
    }
    // lane l and l+32 hold disjoint kk halves for the same q = l31
    lsum += __shfl_xor(lsum, 32);
    if (h == 0) lsums[w][l31] = lsum;
#pragma unroll
    for (int r = 0; r < 16; ++r){
        const int qloc = (r&3) + 8*(r>>2) + 4*h;
        osum[w][qloc][l31]      = o0[r];
        osum[w][qloc][l31 + 32] = o1[r];
    }
    __syncthreads();
    // final: out = (sum_w osum) / (sum_w lsums), written directly
    {
        const int q  = tid >> 3;
        const int e0 = (tid & 7) * 8;
        const float L = lsums[0][q] + lsums[1][q] + lsums[2][q] + lsums[3][q];
        const float inv = 1.0f / L;
        f32x4 r0 = (f32x4){0.f,0.f,0.f,0.f}, r1v = (f32x4){0.f,0.f,0.f,0.f};
#pragma unroll
        for (int ww = 0; ww < 4; ++ww){
            f32x4 a = *(const f32x4*)&osum[ww][q][e0];
            f32x4 b = *(const f32x4*)&osum[ww][q][e0 + 4];
#pragma unroll
            for (int j = 0; j < 4; ++j){ r0[j] += a[j]; r1v[j] += b[j]; }
        }
#pragma unroll
        for (int j = 0; j < 4; ++j){ r0[j] *= inv; r1v[j] *= inv; }
        const int b_ = bh >> 3, hh = bh & 7;
        const size_t ob = ((size_t)(b_*TSEQ + q0 + q))*512 + hh*64 + e0;
        *(f32x4*)&out[ob]     = r0;
        *(f32x4*)&out[ob + 4] = r1v;
    }
}

extern "C" void kernel_launch(void* const* d_in, const int* in_sizes, int n_in,
                              void* d_out, int out_size, void* d_ws, size_t ws_size,
                              hipStream_t stream)
{
    const float* x     = (const float*)d_in[0];
    const float* ln_g  = (const float*)d_in[1];
    const float* ln_b  = (const float*)d_in[2];
    const float* ln_gs = (const float*)d_in[3];
    const float* ln_bs = (const float*)d_in[4];
    const float* ln_ge = (const float*)d_in[5];
    const float* ln_be = (const float*)d_in[6];
    const float* Wq    = (const float*)d_in[7];
    const float* Wk    = (const float*)d_in[8];
    const float* Wv    = (const float*)d_in[9];
    const float* Wq_s  = (const float*)d_in[10];
    const float* Wk_s  = (const float*)d_in[11];
    const float* Wv_s  = (const float*)d_in[12];
    const float* Wq_e  = (const float*)d_in[13];
    const float* Wk_e  = (const float*)d_in[14];
    const float* Wv_e  = (const float*)d_in[15];

    uint8_t* w = (uint8_t*)d_ws;
    unsigned short* nrm = (unsigned short*)(w);                 //  9,437,184 B
    unsigned short* wb  = (unsigned short*)(w + 9437184);       //  9,437,184 B
    float*          bia = (float*)        (w + 18874368);       //     18,432 B
    unsigned short* q_  = (unsigned short*)(w + 18892800);      //  4,718,592 B
    unsigned short* k_  = (unsigned short*)(w + 23611392);      //  4,718,592 B
    unsigned short* vt_ = (unsigned short*)(w + 28329984);      //  4,718,592 B (end 33,048,576)

    WArgs wa;
    wa.W[0] = Wq_s; wa.W[1] = Wk_s; wa.W[2] = Wv_s;
    wa.W[3] = Wq;   wa.W[4] = Wk;   wa.W[5] = Wv;
    wa.W[6] = Wq_e; wa.W[7] = Wk_e; wa.W[8] = Wv_e;
    wa.g[0] = ln_gs; wa.g[1] = ln_g; wa.g[2] = ln_ge;
    wa.bv[0] = ln_bs; wa.bv[1] = ln_b; wa.bv[2] = ln_be;

    float* out = (float*)d_out;
    k_pre <<<dim3(5832),   dim3(256), 0, stream>>>(wa, x, wb, bia, nrm);
    k_gemm<<<dim3(36, 12), dim3(256), 0, stream>>>(nrm, wb, bia, q_, k_, vt_);
    k_attn<<<dim3(1152),   dim3(256), 0, stream>>>(q_, k_, vt_, out);
}

// Round 15
// 98.308 us; speedup vs baseline: 1.3268x; 1.3268x over previous
//
#include <hip/hip_runtime.h>

#define TSEQ 2304
#define DIN  1024
#define NH   8
#define DD   64
#define NC   1536
#define MROWS 4608
#define L2E  1.44269504f
#define EF   2.71828183f

typedef __attribute__((ext_vector_type(8))) short bf16x8;
typedef __attribute__((ext_vector_type(4))) float f32x4;
typedef __attribute__((ext_vector_type(16))) float f32x16;
typedef __attribute__((ext_vector_type(4))) unsigned short u16x4;
typedef __attribute__((ext_vector_type(4))) unsigned int u32x4;

__device__ __forceinline__ unsigned short f2bf(float f){
    union { float f; unsigned int u; } x; x.f = f;
    unsigned int r = x.u + 0x7FFFu + ((x.u >> 16) & 1u);
    return (unsigned short)(r >> 16);
}

// raw v_exp_f32: D = 2^S0, no libm guard code (inputs bounded +-10 here)
__device__ __forceinline__ float exp2raw(float x){
    float r;
    asm("v_exp_f32 %0, %1" : "=v"(r) : "v"(x));
    return r;
}

// two f32 -> packed [bf16(b):bf16(a)] in one VALU op
__device__ __forceinline__ unsigned int cvtpk(float a, float b){
    unsigned int r;
    asm("v_cvt_pk_bf16_f32 %0, %1, %2" : "=v"(r) : "v"(a), "v"(b));
    return r;
}

__device__ __forceinline__ void gload_lds16(const void* g, void* l){
    __builtin_amdgcn_global_load_lds(
        (const __attribute__((address_space(1))) void*)g,
        (__attribute__((address_space(3))) void*)l, 16, 0, 0);
}

struct WArgs {
    const float* W[9];   // [seg*3+proj], seg0=s, seg1=m, seg2=e; proj0=q,1=k,2=v
    const float* g[3];
    const float* bv[3];
};

// Fused preprocessing: blocks [0,1152) build Wb AND bias partials (atomicAdd);
// blocks [1152,5760) do LayerNorm. bias must be zeroed before launch.
__global__ __launch_bounds__(256) void k_pre(WArgs a, const float* __restrict__ x,
                                             unsigned short* __restrict__ wb,
                                             float* __restrict__ bias,
                                             unsigned short* __restrict__ nrm)
{
    __shared__ float lds[64][65];
    __shared__ float red[4][64];
    __shared__ float r1[4], r2[4];
    const int bid = blockIdx.x;
    const int tid = threadIdx.x;
    if (bid < 1152){
        const int dt = bid & 15, h = (bid >> 4) & 7, sp = bid >> 7;
        const int seg = sp / 3, proj = sp % 3;
        const float* W = a.W[seg*3 + proj];
        const float* g = a.g[seg];
        const float* bv = a.bv[seg];
        const int d0 = dt * 64;
        {
            const int e = tid & 63, rq = tid >> 6;
#pragma unroll
            for (int rr = 0; rr < 16; ++rr){
                const int dl = rr*4 + rq;
                lds[dl][e] = W[((size_t)h*DIN + d0 + dl)*DD + e];
            }
        }
        __syncthreads();
        {
            const int dl = tid & 63, eq = tid >> 6;
            const int n0 = proj*512 + h*64;
            const float gv = g[h*DIN + d0 + dl];
#pragma unroll
            for (int rr = 0; rr < 16; ++rr){
                const int el = eq*16 + rr;
                wb[((size_t)seg*NC + n0 + el)*DIN + d0 + dl] = f2bf(lds[dl][el] * gv);
            }
        }
        // bias partial: sum over this block's 64 d of bv[d]*W[d][e]
        {
            const int e = tid & 63, dc = tid >> 6;
            float sum = 0.f;
#pragma unroll
            for (int i = 0; i < 16; ++i){
                const int dl = dc*16 + i;
                sum += bv[h*DIN + d0 + dl] * lds[dl][e];
            }
            red[dc][e] = sum;
            __syncthreads();
            if (dc == 0)
                atomicAdd(&bias[seg*NC + proj*512 + h*64 + e],
                          red[0][e] + red[1][e] + red[2][e] + red[3][e]);
        }
    } else {
        const int row = bid - 1152;
        const float* xr = x + (size_t)row * DIN;
        f32x4 v = *(const f32x4*)&xr[tid*4];
        float s1 = v[0]+v[1]+v[2]+v[3];
        float s2 = v[0]*v[0]+v[1]*v[1]+v[2]*v[2]+v[3]*v[3];
#pragma unroll
        for (int m = 1; m < 64; m <<= 1){ s1 += __shfl_xor(s1, m); s2 += __shfl_xor(s2, m); }
        const int wid = tid >> 6;
        if ((tid & 63) == 0){ r1[wid] = s1; r2[wid] = s2; }
        __syncthreads();
        s1 = r1[0]+r1[1]+r1[2]+r1[3];
        s2 = r2[0]+r2[1]+r2[2]+r2[3];
        const float mean = s1 * (1.f/1024.f);
        const float var  = s2 * (1.f/1024.f) - mean*mean;
        const float rstd = rsqrtf(var + 1e-5f);
        u16x4 ov;
#pragma unroll
        for (int j = 0; j < 4; ++j) ov[j] = f2bf((v[j]-mean)*rstd);
        *(u16x4*)&nrm[(size_t)row*DIN + tid*4] = ov;
    }
}

// C[4608][1536] = nrm @ Wb[seg]^T + bias; q,k scattered to [b][h][t][64];
// V written DIRECTLY TRANSPOSED to vt[b][h][e][t]. q pre-scaled by 0.125*log2e.
// 64x128 tile (M x N) -> grid 72x12 = 864 blocks (3.4/CU, 2x occupancy of
// 128x128). BK=64; LDS XOR slot swizzle via pre-swizzled global source.
__global__ __launch_bounds__(256) void k_gemm(
    const unsigned short* __restrict__ A,
    const unsigned short* __restrict__ Wb,
    const float* __restrict__ bias,
    unsigned short* __restrict__ qo,
    unsigned short* __restrict__ ko,
    unsigned short* __restrict__ vt)
{
    __shared__ unsigned short As[64*64];
    __shared__ unsigned short Bs[128*64];
    const int mt = blockIdx.x, nt = blockIdx.y;
    const int row0 = mt*64, n0 = nt*128;
    const int rloc = row0 % TSEQ;
    const int seg = (rloc < 128) ? 0 : (rloc < 2176 ? 1 : 2);
    const unsigned short* Bp = Wb + (size_t)seg * NC * DIN;
    const int tid = threadIdx.x;
    const int wid = tid >> 6, lane = tid & 63;
    const int wr = wid >> 1, wc = wid & 1;
    const int lr = lane & 15, lg = lane >> 4;
    const int rsub = lane >> 3;
    const int cgx  = (lane & 7) ^ rsub;
    f32x4 acc[2][4];
#pragma unroll
    for (int m = 0; m < 2; ++m)
#pragma unroll
        for (int n = 0; n < 4; ++n) acc[m][n] = (f32x4){0.f,0.f,0.f,0.f};

    for (int kt = 0; kt < DIN/64; ++kt){
        const int k0 = kt*64;
        __syncthreads();
        // A: 8 chunks (2/wave), B: 16 chunks (4/wave); chunk = 8 rows x 128B
#pragma unroll
        for (int i = 0; i < 2; ++i){
            const int c = wid*2 + i;
            gload_lds16(&A[(size_t)(row0 + c*8 + rsub)*DIN + k0 + cgx*8], &As[c*512]);
        }
#pragma unroll
        for (int i = 0; i < 4; ++i){
            const int c = wid*4 + i;
            gload_lds16(&Bp[(size_t)(n0 + c*8 + rsub)*DIN + k0 + cgx*8], &Bs[c*512]);
        }
        __syncthreads();
#pragma unroll
        for (int ks = 0; ks < 2; ++ks){
            bf16x8 af[2], bfr[4];
#pragma unroll
            for (int m = 0; m < 2; ++m)
                af[m]  = *(const bf16x8*)&As[(wr*32 + m*16 + lr)*64 + (((ks*4 + lg) ^ (lr & 7))*8)];
#pragma unroll
            for (int n = 0; n < 4; ++n)
                bfr[n] = *(const bf16x8*)&Bs[(wc*64 + n*16 + lr)*64 + (((ks*4 + lg) ^ (lr & 7))*8)];
#pragma unroll
            for (int m = 0; m < 2; ++m)
#pragma unroll
                for (int n = 0; n < 4; ++n)
                    acc[m][n] = __builtin_amdgcn_mfma_f32_16x16x32_bf16(af[m], bfr[n], acc[m][n], 0, 0, 0);
        }
    }
    const int b_ = row0 / TSEQ;
    const int t0 = row0 - b_ * TSEQ;
#pragma unroll
    for (int m = 0; m < 2; ++m){
#pragma unroll
        for (int n = 0; n < 4; ++n){
            const int nglob = n0 + wc*64 + n*16 + lr;
            const float bs = bias[seg*NC + nglob];
            const int proj = nglob >> 9, hh = (nglob >> 6) & 7, e = nglob & 63;
            if (proj < 2){
                unsigned short* op = (proj == 0) ? qo : ko;
                const float scale = (proj == 0) ? 0.125f * L2E : 1.0f;
                const size_t ob = ((size_t)(b_*NH + hh) * TSEQ) * DD + e;
#pragma unroll
                for (int j = 0; j < 4; ++j){
                    const int t = t0 + wr*32 + m*16 + 4*lg + j;
                    op[ob + (size_t)t * DD] = f2bf((acc[m][n][j] + bs) * scale);
                }
            } else {
                unsigned short* vp = vt + ((size_t)(b_*NH + hh)*DD + e)*TSEQ;
                const int t = t0 + wr*32 + m*16 + 4*lg;
                u16x4 pk;
#pragma unroll
                for (int j = 0; j < 4; ++j) pk[j] = f2bf(acc[m][n][j] + bs);
                *(u16x4*)&vp[t] = pk;
            }
        }
    }
}

// Flash attention, 32x32 MFMA, fully in-register P (R12-proven, 47.3 us).
// 4 waves x 32 q-rows; split-K z=3. Swapped QK^T (mfma(K,Q)) -> lane owns
// S^T[kk 32 values][q=lane&31]; C/D layout row=(r&3)+8*(r>>2)+4*(lane>>5).
// PV A-frag built in-register: 4 cvt_pk + 2 v_permlane32_swap per 16-k step.
__global__ __launch_bounds__(256) void k_attn(
    const unsigned short* __restrict__ Q,
    const unsigned short* __restrict__ K,
    const unsigned short* __restrict__ Vt,
    float* __restrict__ po0,
    float* __restrict__ po1,
    float* __restrict__ out2,
    float* __restrict__ pl)
{
    __shared__ unsigned short Ks[2][64*64];
    __shared__ unsigned short Vs[2][64*64];
    const int qtb = blockIdx.x;  // 18
    const int bh  = blockIdx.y;  // 16
    const int z   = blockIdx.z;  // 3
    const int kt0 = z*12, kt1 = kt0 + 12;
    const int tid  = threadIdx.x;
    const int w    = tid >> 6;
    const int lane = tid & 63;
    const int l31  = lane & 31;
    const int h    = lane >> 5;
    const size_t qkb = (size_t)bh * TSEQ * DD;
    const size_t vtb = (size_t)bh * DD * TSEQ;
    const int q0w = qtb*128 + w*32;
    const int kd  = qtb*2 + (w >> 1);    // wave-uniform diagonal k-tile

    const int rsub = lane >> 3;
    const int cgx  = (lane & 7) ^ rsub;  // inverse swizzle on global source
    const char* Kbase  = (const char*)(K  + qkb);
    const char* Vtbase = (const char*)(Vt + vtb);

    // Q fragments (B-operand): n = q0w + l31, k-slice ds*16 + h*8
    bf16x8 aq[4];
#pragma unroll
    for (int ds = 0; ds < 4; ++ds)
        aq[ds] = *(const bf16x8*)&Q[qkb + (size_t)(q0w + l31)*DD + ds*16 + h*8];

    float lsum = 0.f;
    f32x16 o0, o1;
#pragma unroll
    for (int r = 0; r < 16; ++r){ o0[r] = 0.f; o1[r] = 0.f; }

    auto stage = [&](int kt, int b){
        const int kn = kt*64;
#pragma unroll
        for (int i = 0; i < 2; ++i){
            const int c = w*2 + i;
            const int r = c*8 + rsub;
            gload_lds16(Kbase  + (size_t)(kn + r)*128 + cgx*16,              &Ks[b][c*512]);
            gload_lds16(Vtbase + (size_t)r*(TSEQ*2) + (size_t)kn*2 + cgx*16, &Vs[b][c*512]);
        }
    };

    stage(kt0, 0);
    __syncthreads();

    const int rowA = l31 * 64;   // shorts: row base for K (kk-block0) / V (e-block0)

    int buf = 0;
    for (int kt = kt0; kt < kt1; ++kt){
        const int kc0 = kt*64;
        if (kt + 1 < kt1) stage(kt + 1, buf ^ 1);
        // QK^T: s0 = S^T[kk 0..31][q], s1 = S^T[kk 32..63][q]
        f32x16 s0, s1;
#pragma unroll
        for (int r = 0; r < 16; ++r){ s0[r] = 0.f; s1[r] = 0.f; }
#pragma unroll
        for (int ds = 0; ds < 4; ++ds){
            const int sx = (((ds*2 + h) ^ (lane & 7)) * 8);
            bf16x8 kf0 = *(const bf16x8*)&Ks[buf][rowA + sx];
            bf16x8 kf1 = *(const bf16x8*)&Ks[buf][rowA + 2048 + sx];
            s0 = __builtin_amdgcn_mfma_f32_32x32x16_bf16(kf0, aq[ds], s0, 0, 0, 0);
            s1 = __builtin_amdgcn_mfma_f32_32x32x16_bf16(kf1, aq[ds], s1, 0, 0, 0);
        }
        // softmax numerators (deferred tril bias: x e at diagonal)
        if (kt == kd){
            lsum *= EF;
#pragma unroll
            for (int r = 0; r < 16; ++r){ o0[r] *= EF; o1[r] *= EF; }
            const int qr = q0w + l31;
#pragma unroll
            for (int r = 0; r < 16; ++r){
                const int kk = kc0 + (r&3) + 8*(r>>2) + 4*h;
                const float p0 = exp2raw(s0[r] + ((kk      <= qr) ? L2E : 0.f));
                const float p1 = exp2raw(s1[r] + ((kk + 32 <= qr) ? L2E : 0.f));
                s0[r] = p0; s1[r] = p1;
                lsum += p0 + p1;
            }
        } else {
#pragma unroll
            for (int r = 0; r < 16; ++r){
                const float p0 = exp2raw(s0[r]);
                const float p1 = exp2raw(s1[r]);
                s0[r] = p0; s1[r] = p1;
                lsum += p0 + p1;
            }
        }
        // PV: per 16-k step build A-frag in-register (cvt_pk + permlane32_swap)
#pragma unroll
        for (int ks = 0; ks < 4; ++ks){
            const int rb = (ks & 1) * 8;
            unsigned int a01, a23, b01, b23;
            if (ks < 2){
                a01 = cvtpk(s0[rb+0], s0[rb+1]); a23 = cvtpk(s0[rb+2], s0[rb+3]);
                b01 = cvtpk(s0[rb+4], s0[rb+5]); b23 = cvtpk(s0[rb+6], s0[rb+7]);
            } else {
                a01 = cvtpk(s1[rb+0], s1[rb+1]); a23 = cvtpk(s1[rb+2], s1[rb+3]);
                b01 = cvtpk(s1[rb+4], s1[rb+5]); b23 = cvtpk(s1[rb+6], s1[rb+7]);
            }
            asm("v_permlane32_swap_b32 %0, %1" : "+v"(a01), "+v"(b01));
            asm("v_permlane32_swap_b32 %0, %1" : "+v"(a23), "+v"(b23));
            u32x4 fw; fw[0] = a01; fw[1] = a23; fw[2] = b01; fw[3] = b23;
            bf16x8 pa = __builtin_bit_cast(bf16x8, fw);
            const int sx = (((ks*2 + h) ^ (lane & 7)) * 8);
            bf16x8 vf0 = *(const bf16x8*)&Vs[buf][rowA + sx];
            bf16x8 vf1 = *(const bf16x8*)&Vs[buf][rowA + 2048 + sx];
            o0 = __builtin_amdgcn_mfma_f32_32x32x16_bf16(pa, vf0, o0, 0, 0, 0);
            o1 = __builtin_amdgcn_mfma_f32_32x32x16_bf16(pa, vf1, o1, 0, 0, 0);
        }
        __syncthreads();
        buf ^= 1;
    }
    if (kd >= kt1){
        lsum *= EF;
#pragma unroll
        for (int r = 0; r < 16; ++r){ o0[r] *= EF; o1[r] *= EF; }
    }
    // lane l and l+32 hold disjoint kk halves for the same q = l31
    lsum += __shfl_xor(lsum, 32);
    const int pbase = ((z*16 + bh)*18 + qtb)*128 + w*32;
    if (h == 0) pl[pbase + l31] = lsum;
    if (z < 2){
        float* po = (z == 0) ? po0 : po1;
        const size_t tb = ((size_t)(bh*18 + qtb)*128 + w*32) * 64;
#pragma unroll
        for (int r = 0; r < 16; ++r){
            const int qloc = (r&3) + 8*(r>>2) + 4*h;
            po[tb + (size_t)qloc*64 + l31]      = o0[r];
            po[tb + (size_t)qloc*64 + 32 + l31] = o1[r];
        }
    } else {
        const int b_ = bh >> 3, hh = bh & 7;
#pragma unroll
        for (int r = 0; r < 16; ++r){
            const int qloc = (r&3) + 8*(r>>2) + 4*h;
            const size_t ob = ((size_t)(b_*TSEQ + q0w + qloc))*512 + hh*64;
            out2[ob + l31]      = o0[r];
            out2[ob + 32 + l31] = o1[r];
        }
    }
}

// out = (po0 + po1 + out(po2)) / (pl0 + pl1 + pl2); po2 lives in out-layout
__global__ __launch_bounds__(256) void k_comb(
    const float* __restrict__ po0, const float* __restrict__ po1,
    const float* __restrict__ pl, float* __restrict__ out)
{
    const int qt = blockIdx.x, bh = blockIdx.y;   // 36 x 16
    const int b_ = bh >> 3, hh = bh & 7;
    const int tid = threadIdx.x;
    const int row = tid >> 2;            // 0..63
    const int c0  = (tid & 3) * 16;
    const int t128  = qt >> 1;
    const int rowin = (qt & 1)*64 + row;
    const int plb = (bh*18 + t128)*128 + rowin;
    const float inv = 1.0f / (pl[plb] + pl[(16*18*128) + plb] + pl[(2*16*18*128) + plb]);
    const size_t tb = ((size_t)(bh*18 + t128)*128 + rowin)*64 + c0;
    const size_t ob = ((size_t)(b_*TSEQ + qt*64 + row))*512 + hh*64 + c0;
#pragma unroll
    for (int i = 0; i < 4; ++i){
        f32x4 a = *(const f32x4*)&po0[tb + i*4];
        f32x4 b = *(const f32x4*)&po1[tb + i*4];
        f32x4 c = *(const f32x4*)&out[ob + i*4];
        f32x4 r;
#pragma unroll
        for (int j = 0; j < 4; ++j) r[j] = (a[j] + b[j] + c[j]) * inv;
        *(f32x4*)&out[ob + i*4] = r;
    }
}

extern "C" void kernel_launch(void* const* d_in, const int* in_sizes, int n_in,
                              void* d_out, int out_size, void* d_ws, size_t ws_size,
                              hipStream_t stream)
{
    const float* x     = (const float*)d_in[0];
    const float* ln_g  = (const float*)d_in[1];
    const float* ln_b  = (const float*)d_in[2];
    const float* ln_gs = (const float*)d_in[3];
    const float* ln_bs = (const float*)d_in[4];
    const float* ln_ge = (const float*)d_in[5];
    const float* ln_be = (const float*)d_in[6];
    const float* Wq    = (const float*)d_in[7];
    const float* Wk    = (const float*)d_in[8];
    const float* Wv    = (const float*)d_in[9];
    const float* Wq_s  = (const float*)d_in[10];
    const float* Wk_s  = (const float*)d_in[11];
    const float* Wv_s  = (const float*)d_in[12];
    const float* Wq_e  = (const float*)d_in[13];
    const float* Wk_e  = (const float*)d_in[14];
    const float* Wv_e  = (const float*)d_in[15];

    uint8_t* w = (uint8_t*)d_ws;
    unsigned short* nrm = (unsigned short*)(w);                 //  9,437,184 B
    unsigned short* wb  = (unsigned short*)(w + 9437184);       //  9,437,184 B
    float*          bia = (float*)        (w + 18874368);       //     18,432 B
    unsigned short* q_  = (unsigned short*)(w + 18892800);      //  4,718,592 B
    unsigned short* k_  = (unsigned short*)(w + 23611392);      //  4,718,592 B
    unsigned short* vt_ = (unsigned short*)(w + 28329984);      //  4,718,592 B (end 33,048,576)
    float*          pl  = (float*)        (w + 33048576);       //    442,368 B (end 33,490,944)
    float*          po0 = (float*)        (w);                  //  9,437,184 B -- reuses nrm (dead after k_gemm)
    float*          po1 = (float*)        (w + 9437184);        //  9,437,184 B -- reuses wb  (dead after k_gemm)

    WArgs wa;
    wa.W[0] = Wq_s; wa.W[1] = Wk_s; wa.W[2] = Wv_s;
    wa.W[3] = Wq;   wa.W[4] = Wk;   wa.W[5] = Wv;
    wa.W[6] = Wq_e; wa.W[7] = Wk_e; wa.W[8] = Wv_e;
    wa.g[0] = ln_gs; wa.g[1] = ln_g; wa.g[2] = ln_ge;
    wa.bv[0] = ln_bs; wa.bv[1] = ln_b; wa.bv[2] = ln_be;

    float* out = (float*)d_out;
    hipMemsetAsync(bia, 0, 4608 * sizeof(float), stream);
    k_pre <<<dim3(5760),      dim3(256), 0, stream>>>(wa, x, wb, bia, nrm);
    k_gemm<<<dim3(72, 12),    dim3(256), 0, stream>>>(nrm, wb, bia, q_, k_, vt_);
    k_attn<<<dim3(18, 16, 3), dim3(256), 0, stream>>>(q_, k_, vt_, po0, po1, out, pl);
    k_comb<<<dim3(36, 16),    dim3(256), 0, stream>>>(po0, po1, pl, out);
}

// Round 16
// 97.674 us; speedup vs baseline: 1.3355x; 1.0065x over previous
//
#include <hip/hip_runtime.h>

#define TSEQ 2304
#define DIN  1024
#define NH   8
#define DD   64
#define NC   1536
#define MROWS 4608
#define L2E  1.44269504f
#define EF   2.71828183f

typedef __attribute__((ext_vector_type(8))) short bf16x8;
typedef __attribute__((ext_vector_type(4))) float f32x4;
typedef __attribute__((ext_vector_type(16))) float f32x16;
typedef __attribute__((ext_vector_type(4))) unsigned short u16x4;
typedef __attribute__((ext_vector_type(4))) unsigned int u32x4;

__device__ __forceinline__ unsigned short f2bf(float f){
    union { float f; unsigned int u; } x; x.f = f;
    unsigned int r = x.u + 0x7FFFu + ((x.u >> 16) & 1u);
    return (unsigned short)(r >> 16);
}

// raw v_exp_f32: D = 2^S0, no libm guard code (inputs bounded +-10 here)
__device__ __forceinline__ float exp2raw(float x){
    float r;
    asm("v_exp_f32 %0, %1" : "=v"(r) : "v"(x));
    return r;
}

// two f32 -> packed [bf16(b):bf16(a)] in one VALU op
__device__ __forceinline__ unsigned int cvtpk(float a, float b){
    unsigned int r;
    asm("v_cvt_pk_bf16_f32 %0, %1, %2" : "=v"(r) : "v"(a), "v"(b));
    return r;
}

__device__ __forceinline__ void gload_lds16(const void* g, void* l){
    __builtin_amdgcn_global_load_lds(
        (const __attribute__((address_space(1))) void*)g,
        (__attribute__((address_space(3))) void*)l, 16, 0, 0);
}

struct WArgs {
    const float* W[9];   // [seg*3+proj], seg0=s, seg1=m, seg2=e; proj0=q,1=k,2=v
    const float* g[3];
    const float* bv[3];
};

// Fused preprocessing: blocks [0,1152) build Wb, [1152,1224) bias, [1224,5832) LN
__global__ __launch_bounds__(256) void k_pre(WArgs a, const float* __restrict__ x,
                                             unsigned short* __restrict__ wb,
                                             float* __restrict__ bias,
                                             unsigned short* __restrict__ nrm)
{
    __shared__ float lds[64][65];
    __shared__ float red[4][64];
    __shared__ float r1[4], r2[4];
    const int bid = blockIdx.x;
    const int tid = threadIdx.x;
    if (bid < 1152){
        const int dt = bid & 15, h = (bid >> 4) & 7, sp = bid >> 7;
        const int seg = sp / 3, proj = sp % 3;
        const float* W = a.W[seg*3 + proj];
        const float* g = a.g[seg];
        const int d0 = dt * 64;
        {
            const int e = tid & 63, rq = tid >> 6;
#pragma unroll
            for (int rr = 0; rr < 16; ++rr){
                const int dl = rr*4 + rq;
                lds[dl][e] = W[((size_t)h*DIN + d0 + dl)*DD + e];
            }
        }
        __syncthreads();
        {
            const int dl = tid & 63, eq = tid >> 6;
            const int n0 = proj*512 + h*64;
            const float gv = g[h*DIN + d0 + dl];
#pragma unroll
            for (int rr = 0; rr < 16; ++rr){
                const int el = eq*16 + rr;
                wb[((size_t)seg*NC + n0 + el)*DIN + d0 + dl] = f2bf(lds[dl][el] * gv);
            }
        }
    } else if (bid < 1224){
        const int u = bid - 1152;
        const int h = u & 7, sp = u >> 3;
        const int seg = sp / 3, proj = sp % 3;
        const float* W  = a.W[seg*3 + proj];
        const float* bv = a.bv[seg];
        const int e = tid & 63, dc = tid >> 6;
        float sum = 0.f;
        for (int i = 0; i < 256; ++i){
            const int d = dc*256 + i;
            sum += bv[h*DIN + d] * W[((size_t)h*DIN + d)*DD + e];
        }
        red[dc][e] = sum;
        __syncthreads();
        if (dc == 0)
            bias[seg*NC + proj*512 + h*64 + e] = red[0][e] + red[1][e] + red[2][e] + red[3][e];
    } else {
        const int row = bid - 1224;
        const float* xr = x + (size_t)row * DIN;
        f32x4 v = *(const f32x4*)&xr[tid*4];
        float s1 = v[0]+v[1]+v[2]+v[3];
        float s2 = v[0]*v[0]+v[1]*v[1]+v[2]*v[2]+v[3]*v[3];
#pragma unroll
        for (int m = 1; m < 64; m <<= 1){ s1 += __shfl_xor(s1, m); s2 += __shfl_xor(s2, m); }
        const int wid = tid >> 6;
        if ((tid & 63) == 0){ r1[wid] = s1; r2[wid] = s2; }
        __syncthreads();
        s1 = r1[0]+r1[1]+r1[2]+r1[3];
        s2 = r2[0]+r2[1]+r2[2]+r2[3];
        const float mean = s1 * (1.f/1024.f);
        const float var  = s2 * (1.f/1024.f) - mean*mean;
        const float rstd = rsqrtf(var + 1e-5f);
        u16x4 ov;
#pragma unroll
        for (int j = 0; j < 4; ++j) ov[j] = f2bf((v[j]-mean)*rstd);
        *(u16x4*)&nrm[(size_t)row*DIN + tid*4] = ov;
    }
}

// C[4608][1536] = nrm @ Wb[seg]^T + bias; q,k scattered to [b][h][t][64];
// V written DIRECTLY TRANSPOSED to vt[b][h][e][t]. q pre-scaled by 0.125*log2e.
// BK=64; [128][64] LDS with XOR slot swizzle via pre-swizzled global source.
__global__ __launch_bounds__(256) void k_gemm(
    const unsigned short* __restrict__ A,
    const unsigned short* __restrict__ Wb,
    const float* __restrict__ bias,
    unsigned short* __restrict__ qo,
    unsigned short* __restrict__ ko,
    unsigned short* __restrict__ vt)
{
    __shared__ unsigned short As[128*64];
    __shared__ unsigned short Bs[128*64];
    const int mt = blockIdx.x, nt = blockIdx.y;
    const int row0 = mt*128, n0 = nt*128;
    const int rloc = row0 % TSEQ;
    const int seg = (rloc < 128) ? 0 : (rloc < 2176 ? 1 : 2);
    const unsigned short* Bp = Wb + (size_t)seg * NC * DIN;
    const int tid = threadIdx.x;
    const int wid = tid >> 6, lane = tid & 63;
    const int wr = wid >> 1, wc = wid & 1;
    const int lr = lane & 15, lg = lane >> 4;
    const int rsub = lane >> 3;
    const int cgx  = (lane & 7) ^ rsub;
    f32x4 acc[4][4];
#pragma unroll
    for (int m = 0; m < 4; ++m)
#pragma unroll
        for (int n = 0; n < 4; ++n) acc[m][n] = (f32x4){0.f,0.f,0.f,0.f};

    for (int kt = 0; kt < DIN/64; ++kt){
        const int k0 = kt*64;
        __syncthreads();
#pragma unroll
        for (int i = 0; i < 4; ++i){
            const int c = wid*4 + i;
            const int r = c*8 + rsub;
            gload_lds16(&A [(size_t)(row0 + r)*DIN + k0 + cgx*8], &As[c*512]);
            gload_lds16(&Bp[(size_t)(n0  + r)*DIN + k0 + cgx*8], &Bs[c*512]);
        }
        __syncthreads();
#pragma unroll
        for (int ks = 0; ks < 2; ++ks){
            bf16x8 af[4], bfr[4];
#pragma unroll
            for (int m = 0; m < 4; ++m)
                af[m]  = *(const bf16x8*)&As[(wr*64 + m*16 + lr)*64 + (((ks*4 + lg) ^ (lr & 7))*8)];
#pragma unroll
            for (int n = 0; n < 4; ++n)
                bfr[n] = *(const bf16x8*)&Bs[(wc*64 + n*16 + lr)*64 + (((ks*4 + lg) ^ (lr & 7))*8)];
#pragma unroll
            for (int m = 0; m < 4; ++m)
#pragma unroll
                for (int n = 0; n < 4; ++n)
                    acc[m][n] = __builtin_amdgcn_mfma_f32_16x16x32_bf16(af[m], bfr[n], acc[m][n], 0, 0, 0);
        }
    }
    const int b_ = row0 / TSEQ;
    const int t0 = row0 - b_ * TSEQ;
#pragma unroll
    for (int m = 0; m < 4; ++m){
#pragma unroll
        for (int n = 0; n < 4; ++n){
            const int nglob = n0 + wc*64 + n*16 + lr;
            const float bs = bias[seg*NC + nglob];
            const int proj = nglob >> 9, hh = (nglob >> 6) & 7, e = nglob & 63;
            if (proj < 2){
                unsigned short* op = (proj == 0) ? qo : ko;
                const float scale = (proj == 0) ? 0.125f * L2E : 1.0f;
                const size_t ob = ((size_t)(b_*NH + hh) * TSEQ) * DD + e;
#pragma unroll
                for (int j = 0; j < 4; ++j){
                    const int t = t0 + wr*64 + m*16 + 4*lg + j;
                    op[ob + (size_t)t * DD] = f2bf((acc[m][n][j] + bs) * scale);
                }
            } else {
                unsigned short* vp = vt + ((size_t)(b_*NH + hh)*DD + e)*TSEQ;
                const int t = t0 + wr*64 + m*16 + 4*lg;
                u16x4 pk;
#pragma unroll
                for (int j = 0; j < 4; ++j) pk[j] = f2bf(acc[m][n][j] + bs);
                *(u16x4*)&vp[t] = pk;
            }
        }
    }
}

// Flash attention, 32x32 MFMA, fully in-register P (R12-proven structure) +
// s_setprio(1) around the QK and PV MFMA clusters (T5: cross-block phase
// arbitration; blocks on a CU drift out of phase, priority keeps the matrix
// pipe fed while other blocks are in their VALU softmax phase).
__global__ __launch_bounds__(256) void k_attn(
    const unsigned short* __restrict__ Q,
    const unsigned short* __restrict__ K,
    const unsigned short* __restrict__ Vt,
    float* __restrict__ po0,
    float* __restrict__ po1,
    float* __restrict__ out2,
    float* __restrict__ pl)
{
    __shared__ unsigned short Ks[2][64*64];
    __shared__ unsigned short Vs[2][64*64];
    const int qtb = blockIdx.x;  // 18
    const int bh  = blockIdx.y;  // 16
    const int z   = blockIdx.z;  // 3
    const int kt0 = z*12, kt1 = kt0 + 12;
    const int tid  = threadIdx.x;
    const int w    = tid >> 6;
    const int lane = tid & 63;
    const int l31  = lane & 31;
    const int h    = lane >> 5;
    const size_t qkb = (size_t)bh * TSEQ * DD;
    const size_t vtb = (size_t)bh * DD * TSEQ;
    const int q0w = qtb*128 + w*32;
    const int kd  = qtb*2 + (w >> 1);    // wave-uniform diagonal k-tile

    const int rsub = lane >> 3;
    const int cgx  = (lane & 7) ^ rsub;  // inverse swizzle on global source
    const char* Kbase  = (const char*)(K  + qkb);
    const char* Vtbase = (const char*)(Vt + vtb);

    // Q fragments (B-operand): n = q0w + l31, k-slice ds*16 + h*8
    bf16x8 aq[4];
#pragma unroll
    for (int ds = 0; ds < 4; ++ds)
        aq[ds] = *(const bf16x8*)&Q[qkb + (size_t)(q0w + l31)*DD + ds*16 + h*8];

    float lsum = 0.f;
    f32x16 o0, o1;
#pragma unroll
    for (int r = 0; r < 16; ++r){ o0[r] = 0.f; o1[r] = 0.f; }

    auto stage = [&](int kt, int b){
        const int kn = kt*64;
#pragma unroll
        for (int i = 0; i < 2; ++i){
            const int c = w*2 + i;
            const int r = c*8 + rsub;
            gload_lds16(Kbase  + (size_t)(kn + r)*128 + cgx*16,              &Ks[b][c*512]);
            gload_lds16(Vtbase + (size_t)r*(TSEQ*2) + (size_t)kn*2 + cgx*16, &Vs[b][c*512]);
        }
    };

    stage(kt0, 0);
    __syncthreads();

    const int rowA = l31 * 64;   // shorts: row base for K (kk-block0) / V (e-block0)

    int buf = 0;
    for (int kt = kt0; kt < kt1; ++kt){
        const int kc0 = kt*64;
        if (kt + 1 < kt1) stage(kt + 1, buf ^ 1);
        // QK^T: s0 = S^T[kk 0..31][q], s1 = S^T[kk 32..63][q]
        f32x16 s0, s1;
#pragma unroll
        for (int r = 0; r < 16; ++r){ s0[r] = 0.f; s1[r] = 0.f; }
        __builtin_amdgcn_s_setprio(1);
#pragma unroll
        for (int ds = 0; ds < 4; ++ds){
            const int sx = (((ds*2 + h) ^ (lane & 7)) * 8);
            bf16x8 kf0 = *(const bf16x8*)&Ks[buf][rowA + sx];
            bf16x8 kf1 = *(const bf16x8*)&Ks[buf][rowA + 2048 + sx];
            s0 = __builtin_amdgcn_mfma_f32_32x32x16_bf16(kf0, aq[ds], s0, 0, 0, 0);
            s1 = __builtin_amdgcn_mfma_f32_32x32x16_bf16(kf1, aq[ds], s1, 0, 0, 0);
        }
        __builtin_amdgcn_s_setprio(0);
        // softmax numerators (deferred tril bias: x e at diagonal)
        if (kt == kd){
            lsum *= EF;
#pragma unroll
            for (int r = 0; r < 16; ++r){ o0[r] *= EF; o1[r] *= EF; }
            const int qr = q0w + l31;
#pragma unroll
            for (int r = 0; r < 16; ++r){
                const int kk = kc0 + (r&3) + 8*(r>>2) + 4*h;
                const float p0 = exp2raw(s0[r] + ((kk      <= qr) ? L2E : 0.f));
                const float p1 = exp2raw(s1[r] + ((kk + 32 <= qr) ? L2E : 0.f));
                s0[r] = p0; s1[r] = p1;
                lsum += p0 + p1;
            }
        } else {
#pragma unroll
            for (int r = 0; r < 16; ++r){
                const float p0 = exp2raw(s0[r]);
                const float p1 = exp2raw(s1[r]);
                s0[r] = p0; s1[r] = p1;
                lsum += p0 + p1;
            }
        }
        // PV: per 16-k step build A-frag in-register (cvt_pk + permlane32_swap)
        __builtin_amdgcn_s_setprio(1);
#pragma unroll
        for (int ks = 0; ks < 4; ++ks){
            const int rb = (ks & 1) * 8;
            unsigned int a01, a23, b01, b23;
            if (ks < 2){
                a01 = cvtpk(s0[rb+0], s0[rb+1]); a23 = cvtpk(s0[rb+2], s0[rb+3]);
                b01 = cvtpk(s0[rb+4], s0[rb+5]); b23 = cvtpk(s0[rb+6], s0[rb+7]);
            } else {
                a01 = cvtpk(s1[rb+0], s1[rb+1]); a23 = cvtpk(s1[rb+2], s1[rb+3]);
                b01 = cvtpk(s1[rb+4], s1[rb+5]); b23 = cvtpk(s1[rb+6], s1[rb+7]);
            }
            asm("v_permlane32_swap_b32 %0, %1" : "+v"(a01), "+v"(b01));
            asm("v_permlane32_swap_b32 %0, %1" : "+v"(a23), "+v"(b23));
            u32x4 fw; fw[0] = a01; fw[1] = a23; fw[2] = b01; fw[3] = b23;
            bf16x8 pa = __builtin_bit_cast(bf16x8, fw);
            const int sx = (((ks*2 + h) ^ (lane & 7)) * 8);
            bf16x8 vf0 = *(const bf16x8*)&Vs[buf][rowA + sx];
            bf16x8 vf1 = *(const bf16x8*)&Vs[buf][rowA + 2048 + sx];
            o0 = __builtin_amdgcn_mfma_f32_32x32x16_bf16(pa, vf0, o0, 0, 0, 0);
            o1 = __builtin_amdgcn_mfma_f32_32x32x16_bf16(pa, vf1, o1, 0, 0, 0);
        }
        __builtin_amdgcn_s_setprio(0);
        __syncthreads();
        buf ^= 1;
    }
    if (kd >= kt1){
        lsum *= EF;
#pragma unroll
        for (int r = 0; r < 16; ++r){ o0[r] *= EF; o1[r] *= EF; }
    }
    // lane l and l+32 hold disjoint kk halves for the same q = l31
    lsum += __shfl_xor(lsum, 32);
    const int pbase = ((z*16 + bh)*18 + qtb)*128 + w*32;
    if (h == 0) pl[pbase + l31] = lsum;
    if (z < 2){
        float* po = (z == 0) ? po0 : po1;
        const size_t tb = ((size_t)(bh*18 + qtb)*128 + w*32) * 64;
#pragma unroll
        for (int r = 0; r < 16; ++r){
            const int qloc = (r&3) + 8*(r>>2) + 4*h;
            po[tb + (size_t)qloc*64 + l31]      = o0[r];
            po[tb + (size_t)qloc*64 + 32 + l31] = o1[r];
        }
    } else {
        const int b_ = bh >> 3, hh = bh & 7;
#pragma unroll
        for (int r = 0; r < 16; ++r){
            const int qloc = (r&3) + 8*(r>>2) + 4*h;
            const size_t ob = ((size_t)(b_*TSEQ + q0w + qloc))*512 + hh*64;
            out2[ob + l31]      = o0[r];
            out2[ob + 32 + l31] = o1[r];
        }
    }
}

// out = (po0 + po1 + out(po2)) / (pl0 + pl1 + pl2); po2 lives in out-layout
__global__ __launch_bounds__(256) void k_comb(
    const float* __restrict__ po0, const float* __restrict__ po1,
    const float* __restrict__ pl, float* __restrict__ out)
{
    const int qt = blockIdx.x, bh = blockIdx.y;   // 36 x 16
    const int b_ = bh >> 3, hh = bh & 7;
    const int tid = threadIdx.x;
    const int row = tid >> 2;            // 0..63
    const int c0  = (tid & 3) * 16;
    const int t128  = qt >> 1;
    const int rowin = (qt & 1)*64 + row;
    const int plb = (bh*18 + t128)*128 + rowin;
    const float inv = 1.0f / (pl[plb] + pl[(16*18*128) + plb] + pl[(2*16*18*128) + plb]);
    const size_t tb = ((size_t)(bh*18 + t128)*128 + rowin)*64 + c0;
    const size_t ob = ((size_t)(b_*TSEQ + qt*64 + row))*512 + hh*64 + c0;
#pragma unroll
    for (int i = 0; i < 4; ++i){
        f32x4 a = *(const f32x4*)&po0[tb + i*4];
        f32x4 b = *(const f32x4*)&po1[tb + i*4];
        f32x4 c = *(const f32x4*)&out[ob + i*4];
        f32x4 r;
#pragma unroll
        for (int j = 0; j < 4; ++j) r[j] = (a[j] + b[j] + c[j]) * inv;
        *(f32x4*)&out[ob + i*4] = r;
    }
}

extern "C" void kernel_launch(void* const* d_in, const int* in_sizes, int n_in,
                              void* d_out, int out_size, void* d_ws, size_t ws_size,
                              hipStream_t stream)
{
    const float* x     = (const float*)d_in[0];
    const float* ln_g  = (const float*)d_in[1];
    const float* ln_b  = (const float*)d_in[2];
    const float* ln_gs = (const float*)d_in[3];
    const float* ln_bs = (const float*)d_in[4];
    const float* ln_ge = (const float*)d_in[5];
    const float* ln_be = (const float*)d_in[6];
    const float* Wq    = (const float*)d_in[7];
    const float* Wk    = (const float*)d_in[8];
    const float* Wv    = (const float*)d_in[9];
    const float* Wq_s  = (const float*)d_in[10];
    const float* Wk_s  = (const float*)d_in[11];
    const float* Wv_s  = (const float*)d_in[12];
    const float* Wq_e  = (const float*)d_in[13];
    const float* Wk_e  = (const float*)d_in[14];
    const float* Wv_e  = (const float*)d_in[15];

    uint8_t* w = (uint8_t*)d_ws;
    unsigned short* nrm = (unsigned short*)(w);                 //  9,437,184 B
    unsigned short* wb  = (unsigned short*)(w + 9437184);       //  9,437,184 B
    float*          bia = (float*)        (w + 18874368);       //     18,432 B
    unsigned short* q_  = (unsigned short*)(w + 18892800);      //  4,718,592 B
    unsigned short* k_  = (unsigned short*)(w + 23611392);      //  4,718,592 B
    unsigned short* vt_ = (unsigned short*)(w + 28329984);      //  4,718,592 B (end 33,048,576)
    float*          pl  = (float*)        (w + 33048576);       //    442,368 B (end 33,490,944)
    float*          po0 = (float*)        (w);                  //  9,437,184 B -- reuses nrm (dead after k_gemm)
    float*          po1 = (float*)        (w + 9437184);        //  9,437,184 B -- reuses wb  (dead after k_gemm)

    WArgs wa;
    wa.W[0] = Wq_s; wa.W[1] = Wk_s; wa.W[2] = Wv_s;
    wa.W[3] = Wq;   wa.W[4] = Wk;   wa.W[5] = Wv;
    wa.W[6] = Wq_e; wa.W[7] = Wk_e; wa.W[8] = Wv_e;
    wa.g[0] = ln_gs; wa.g[1] = ln_g; wa.g[2] = ln_ge;
    wa.bv[0] = ln_bs; wa.bv[1] = ln_b; wa.bv[2] = ln_be;

    float* out = (float*)d_out;
    k_pre <<<dim3(5832),      dim3(256), 0, stream>>>(wa, x, wb, bia, nrm);
    k_gemm<<<dim3(36, 12),    dim3(256), 0, stream>>>(nrm, wb, bia, q_, k_, vt_);
    k_attn<<<dim3(18, 16, 3), dim3(256), 0, stream>>>(q_, k_, vt_, po0, po1, out, pl);
    k_comb<<<dim3(36, 16),    dim3(256), 0, stream>>>(po0, po1, pl, out);
}